// Round 4
// baseline (587.243 us; speedup 1.0000x reference)
//
#include <hip/hip_runtime.h>
#include <math.h>

#define B_ 8
#define T_ 2048
#define D_ 2048
#define H_ 128
#define M_ (B_ * T_)

typedef __bf16 bf16x8 __attribute__((ext_vector_type(8)));
typedef __bf16 bf16x4 __attribute__((ext_vector_type(4)));
typedef float f32x4 __attribute__((ext_vector_type(4)));

#define MFMA(a, b, c) __builtin_amdgcn_mfma_f32_16x16x32_bf16(a, b, c, 0, 0, 0)

// ws layout (bf16 elements)
#define QH_OFF 0
#define QL_OFF (1 * 2097152)  // M_*H_
#define KH_OFF (2 * 2097152)
#define KL_OFF (3 * 2097152)
#define VT_OFF (4 * 2097152)        // vt[b][h][t]
#define WTH_OFF (5 * 2097152)       // wt_hi[z*128+n][k]
#define WTL_OFF (WTH_OFF + 786432)  // 3*128*2048

// ---------------- prep: W[k][n] fp32 -> Wt_hi/lo[n][k] bf16 ----------------
__global__ __launch_bounds__(256) void prep_kernel(
    const float* __restrict__ Wq, const float* __restrict__ Wk,
    const float* __restrict__ Wv, __bf16* __restrict__ wt_hi,
    __bf16* __restrict__ wt_lo) {
  const int z = blockIdx.y;
  const int k0 = blockIdx.x * 64;
  const float* W = z == 0 ? Wq : z == 1 ? Wk : Wv;
  __shared__ float tile[64][132];
  const int t = threadIdx.x;
#pragma unroll
  for (int it = 0; it < 8; ++it) {
    int f4 = it * 256 + t;  // 2048 float4 = 64 rows x 32
    int row = f4 >> 5, c = (f4 & 31) << 2;
    *(float4*)&tile[row][c] = *(const float4*)&W[(size_t)(k0 + row) * H_ + c];
  }
  __syncthreads();
  int n = t >> 1, kh = (t & 1) << 5;
  __bf16 h[32], l[32];
#pragma unroll
  for (int kk = 0; kk < 32; ++kk) {
    float x = tile[kh + kk][n];
    __bf16 hi = (__bf16)x;
    h[kk] = hi;
    l[kk] = (__bf16)(x - (float)hi);
  }
  size_t base = (size_t)(z * H_ + n) * D_ + k0 + kh;
#pragma unroll
  for (int c = 0; c < 4; ++c) {
    *(bf16x8*)&wt_hi[base + c * 8] = *(bf16x8*)&h[c * 8];
    *(bf16x8*)&wt_lo[base + c * 8] = *(bf16x8*)&l[c * 8];
  }
}

// ---------------- proj: barrier-free wave-synchronous split-bf16 MFMA ------
// grid (2 strips, 256 m-tiles), 512 thr = 8 waves. Wave (wm=w&1, wn=w>>1):
// 32m x 48n tile. Each wave stages its own 32x32 X slice into wave-private
// LDS (hi/lo, stride 40 -> worst 2-way conflicts). NO __syncthreads in the
// k-loop: within-wave vmcnt/lgkmcnt ordering only, loads stay in flight.
__global__ __launch_bounds__(512, 4) void proj_kernel(
    const float* __restrict__ X, const __bf16* __restrict__ wt_hi,
    const __bf16* __restrict__ wt_lo, __bf16* __restrict__ qh,
    __bf16* __restrict__ ql, __bf16* __restrict__ kh,
    __bf16* __restrict__ kl, __bf16* __restrict__ vt) {
  const int strip = blockIdx.x;
  const int m0 = blockIdx.y * 64;
  __shared__ __align__(16) __bf16 Xh[8][32 * 40];
  __shared__ __align__(16) __bf16 Xl[8][32 * 40];
  const int t = threadIdx.x;
  const int wv = t >> 6, lane = t & 63;
  const int wm = wv & 1, wn = wv >> 1;
  const int l15 = lane & 15, quad = lane >> 4;
  const int nb = strip * 192 + wn * 48;
  const int r = lane >> 1, kc = (lane & 1) << 4;  // lane's 16-float segment
  const float* xrow = X + (size_t)(m0 + wm * 32 + r) * D_ + kc;
  __bf16* xh = &Xh[wv][0];
  __bf16* xl = &Xl[wv][0];
  f32x4 acc[2][3] = {};
  float4 x0 = *(const float4*)(xrow + 0);
  float4 x1 = *(const float4*)(xrow + 4);
  float4 x2 = *(const float4*)(xrow + 8);
  float4 x3 = *(const float4*)(xrow + 12);
  for (int ks = 0; ks < 64; ++ks) {
    {  // convert current X regs -> wave-private LDS (hi/lo)
      float f[16] = {x0.x, x0.y, x0.z, x0.w, x1.x, x1.y, x1.z, x1.w,
                     x2.x, x2.y, x2.z, x2.w, x3.x, x3.y, x3.z, x3.w};
      __bf16 hb[16], lb[16];
#pragma unroll
      for (int i = 0; i < 16; ++i) {
        __bf16 hi = (__bf16)f[i];
        hb[i] = hi;
        lb[i] = (__bf16)(f[i] - (float)hi);
      }
      *(bf16x8*)&xh[r * 40 + kc] = *(bf16x8*)&hb[0];
      *(bf16x8*)&xh[r * 40 + kc + 8] = *(bf16x8*)&hb[8];
      *(bf16x8*)&xl[r * 40 + kc] = *(bf16x8*)&lb[0];
      *(bf16x8*)&xl[r * 40 + kc + 8] = *(bf16x8*)&lb[8];
    }
    if (ks < 63) {  // prefetch next X slice (in flight across rest of iter)
      const float* p = xrow + (ks + 1) * 32;
      x0 = *(const float4*)(p + 0);
      x1 = *(const float4*)(p + 4);
      x2 = *(const float4*)(p + 8);
      x3 = *(const float4*)(p + 12);
    }
    bf16x8 ah[2], al[2];
#pragma unroll
    for (int mg = 0; mg < 2; ++mg) {
      ah[mg] = *(bf16x8*)&xh[(mg * 16 + l15) * 40 + quad * 8];
      al[mg] = *(bf16x8*)&xl[(mg * 16 + l15) * 40 + quad * 8];
    }
#pragma unroll
    for (int nt = 0; nt < 3; ++nt) {
      size_t woff = (size_t)(nb + nt * 16 + l15) * D_ + ks * 32 + quad * 8;
      bf16x8 bh = *(const bf16x8*)(wt_hi + woff);
      bf16x8 bl = *(const bf16x8*)(wt_lo + woff);
#pragma unroll
      for (int mg = 0; mg < 2; ++mg) {
        acc[mg][nt] = MFMA(ah[mg], bh, acc[mg][nt]);
        acc[mg][nt] = MFMA(al[mg], bh, acc[mg][nt]);
        acc[mg][nt] = MFMA(ah[mg], bl, acc[mg][nt]);
      }
    }
  }
  // epilogue
#pragma unroll
  for (int nt = 0; nt < 3; ++nt) {
    int ncb = nb + nt * 16;  // 16-aligned, never crosses a z boundary
    int z = ncb >> 7;
    int h = (ncb & 127) + l15;
#pragma unroll
    for (int mg = 0; mg < 2; ++mg) {
      int r0 = m0 + wm * 32 + mg * 16 + quad * 4;
      if (z == 2) {
        int b = m0 >> 11;
        int tt0 = (m0 & 2047) + wm * 32 + mg * 16 + quad * 4;
        bf16x4 pv = {(__bf16)acc[mg][nt][0], (__bf16)acc[mg][nt][1],
                     (__bf16)acc[mg][nt][2], (__bf16)acc[mg][nt][3]};
        *(bf16x4*)&vt[(size_t)(b * H_ + h) * T_ + tt0] = pv;
      } else {
        __bf16* dh = z == 0 ? qh : kh;
        __bf16* dl = z == 0 ? ql : kl;
#pragma unroll
        for (int reg = 0; reg < 4; ++reg) {
          float v = acc[mg][nt][reg];
          __bf16 hi = (__bf16)v;
          dh[(size_t)(r0 + reg) * H_ + h] = hi;
          dl[(size_t)(r0 + reg) * H_ + h] = (__bf16)(v - (float)hi);
        }
      }
    }
  }
}

// ---------------- attention: two-phase complementary flash ----------------
// 256 blocks x 512 thr. Block (b, pi) runs phase0 = subtile 63-pi with ALL
// 8 waves (round-robin key-tiles), merges, then phase1 = subtile pi.
// ceil(a/8)+ceil(b/8), a+b=33 -> uniformly 5 kt-units per block.
__global__ __launch_bounds__(512, 1) void attn_kernel(
    const __bf16* __restrict__ qh, const __bf16* __restrict__ qlo,
    const __bf16* __restrict__ kh, const __bf16* __restrict__ klo,
    const __bf16* __restrict__ vt, float* __restrict__ out) {
  const int t = threadIdx.x;
  const int wv = t >> 6;
  const int lane = t & 63, l15 = lane & 15, quad = lane >> 4;
  const int j = blockIdx.x, b = j >> 5, pi = j & 31;
  __shared__ __align__(16) __bf16 Pbuf[8][32 * 72];
  __shared__ __align__(16) float Obuf[32 * 132];
  __shared__ float mlb[8][32], llb[8][32];
  const __bf16* vtb = vt + (size_t)b * H_ * T_;
  const float scale = 11.313708498984761f;  // sqrt(128); ref multiplies

  for (int ph = 0; ph < 2; ++ph) {
    if (ph) __syncthreads();  // prev phase's out-write done before reuse
    const int qlidx = ph == 0 ? 63 - pi : pi;
    const int t0 = qlidx * 32;
    const int nkt = (qlidx >> 1) + 1;
    const bool active = (wv < nkt);
    const size_t qrow0 = (size_t)b * T_ + t0;
    bf16x8 qfh[2][4], qfl[2][4];
#pragma unroll
    for (int mg = 0; mg < 2; ++mg)
#pragma unroll
      for (int ds = 0; ds < 4; ++ds) {
        size_t off = (qrow0 + mg * 16 + l15) * H_ + ds * 32 + quad * 8;
        qfh[mg][ds] = *(const bf16x8*)(qh + off);
        qfl[mg][ds] = *(const bf16x8*)(qlo + off);
      }
    f32x4 O[2][8] = {};
    float ms[2][4], ls[2][4];
#pragma unroll
    for (int mg = 0; mg < 2; ++mg)
#pragma unroll
      for (int reg = 0; reg < 4; ++reg) {
        ms[mg][reg] = -INFINITY;
        ls[mg][reg] = 0.f;
      }
    for (int kt_i = wv; kt_i < nkt; kt_i += 8) {
      const int kt = kt_i * 64;
      f32x4 S[2][4] = {};
#pragma unroll
      for (int ds = 0; ds < 4; ++ds)
#pragma unroll
        for (int ct = 0; ct < 4; ++ct) {
          size_t koff =
              ((size_t)b * T_ + kt + ct * 16 + l15) * H_ + ds * 32 + quad * 8;
          bf16x8 bh = *(const bf16x8*)(kh + koff);
          bf16x8 bl = *(const bf16x8*)(klo + koff);
#pragma unroll
          for (int mg = 0; mg < 2; ++mg) {
            S[mg][ct] = MFMA(qfh[mg][ds], bh, S[mg][ct]);
            S[mg][ct] = MFMA(qfl[mg][ds], bh, S[mg][ct]);
            S[mg][ct] = MFMA(qfh[mg][ds], bl, S[mg][ct]);
          }
        }
      const bool diag = (kt_i == nkt - 1);
#pragma unroll
      for (int mg = 0; mg < 2; ++mg)
#pragma unroll
        for (int ct = 0; ct < 4; ++ct)
#pragma unroll
          for (int reg = 0; reg < 4; ++reg) {
            float s = S[mg][ct][reg] * scale;
            if (diag && (kt + ct * 16 + l15 > t0 + mg * 16 + quad * 4 + reg))
              s = -1e30f;
            S[mg][ct][reg] = s;
          }
      float al_[2][4];
#pragma unroll
      for (int mg = 0; mg < 2; ++mg)
#pragma unroll
        for (int reg = 0; reg < 4; ++reg) {
          float r = fmaxf(fmaxf(S[mg][0][reg], S[mg][1][reg]),
                          fmaxf(S[mg][2][reg], S[mg][3][reg]));
          r = fmaxf(r, __shfl_xor(r, 1));
          r = fmaxf(r, __shfl_xor(r, 2));
          r = fmaxf(r, __shfl_xor(r, 4));
          r = fmaxf(r, __shfl_xor(r, 8));
          float mn = fmaxf(ms[mg][reg], r);
          float a = __expf(ms[mg][reg] - mn);
          ms[mg][reg] = mn;
          float ps = 0.f;
#pragma unroll
          for (int ct = 0; ct < 4; ++ct) {
            float p = __expf(S[mg][ct][reg] - mn);
            S[mg][ct][reg] = p;
            ps += p;
          }
          ps += __shfl_xor(ps, 1);
          ps += __shfl_xor(ps, 2);
          ps += __shfl_xor(ps, 4);
          ps += __shfl_xor(ps, 8);
          ls[mg][reg] = ls[mg][reg] * a + ps;
          al_[mg][reg] = a;
        }
#pragma unroll
      for (int mg = 0; mg < 2; ++mg)
#pragma unroll
        for (int ht = 0; ht < 8; ++ht)
#pragma unroll
          for (int reg = 0; reg < 4; ++reg) O[mg][ht][reg] *= al_[mg][reg];
      // P (C-layout) -> wave-private LDS -> A-layout bf16
#pragma unroll
      for (int mg = 0; mg < 2; ++mg)
#pragma unroll
        for (int ct = 0; ct < 4; ++ct)
#pragma unroll
          for (int reg = 0; reg < 4; ++reg)
            Pbuf[wv][(mg * 16 + quad * 4 + reg) * 72 + ct * 16 + l15] =
                (__bf16)S[mg][ct][reg];
#pragma unroll
      for (int ks = 0; ks < 2; ++ks) {
        bf16x8 pf0 = *(bf16x8*)&Pbuf[wv][(l15)*72 + ks * 32 + quad * 8];
        bf16x8 pf1 = *(bf16x8*)&Pbuf[wv][(16 + l15) * 72 + ks * 32 + quad * 8];
#pragma unroll
        for (int ht = 0; ht < 8; ++ht) {
          bf16x8 vf = *(const bf16x8*)&vtb[(size_t)(ht * 16 + l15) * T_ + kt +
                                           ks * 32 + quad * 8];
          O[0][ht] = MFMA(pf0, vf, O[0][ht]);
          O[1][ht] = MFMA(pf1, vf, O[1][ht]);
        }
      }
    }
    // -------- merge the 8 key-chunk waves --------
    if (l15 == 0) {
#pragma unroll
      for (int mg = 0; mg < 2; ++mg)
#pragma unroll
        for (int reg = 0; reg < 4; ++reg) {
          mlb[wv][mg * 16 + quad * 4 + reg] = ms[mg][reg];
          llb[wv][mg * 16 + quad * 4 + reg] = ls[mg][reg];
        }
    }
    for (int i = t; i < 32 * 132; i += 512) Obuf[i] = 0.f;
    __syncthreads();
    if (active) {
      float aw[2][4];
#pragma unroll
      for (int mg = 0; mg < 2; ++mg)
#pragma unroll
        for (int reg = 0; reg < 4; ++reg) {
          int row = mg * 16 + quad * 4 + reg;
          float M = -INFINITY;
#pragma unroll
          for (int w = 0; w < 8; ++w) M = fmaxf(M, mlb[w][row]);
          float L = 0.f;
#pragma unroll
          for (int w = 0; w < 8; ++w)
            L += llb[w][row] * __expf(mlb[w][row] - M);
          aw[mg][reg] = __expf(ms[mg][reg] - M) / L;
        }
#pragma unroll
      for (int mg = 0; mg < 2; ++mg)
#pragma unroll
        for (int ht = 0; ht < 8; ++ht)
#pragma unroll
          for (int reg = 0; reg < 4; ++reg)
            atomicAdd(&Obuf[(mg * 16 + quad * 4 + reg) * 132 + ht * 16 + l15],
                      O[mg][ht][reg] * aw[mg][reg]);
    }
    __syncthreads();
    // -------- write out (fp32, coalesced): 1024 float4 / 512 thr --------
    {
      const size_t obase = ((size_t)b * T_ + t0) * H_;
#pragma unroll
      for (int i = 0; i < 2; ++i) {
        int f4 = i * 512 + t;
        int row = f4 >> 5, c = (f4 & 31) << 2;
        *(float4*)&out[obase + (size_t)row * H_ + c] =
            *(float4*)&Obuf[row * 132 + c];
      }
    }
  }
}

extern "C" void kernel_launch(void* const* d_in, const int* in_sizes, int n_in,
                              void* d_out, int out_size, void* d_ws, size_t ws_size,
                              hipStream_t stream) {
  const float* x = (const float*)d_in[0];
  const float* Wq = (const float*)d_in[1];
  const float* Wk = (const float*)d_in[2];
  const float* Wv = (const float*)d_in[3];
  __bf16* ws = (__bf16*)d_ws;
  float* out = (float*)d_out;
  prep_kernel<<<dim3(32, 3), 256, 0, stream>>>(Wq, Wk, Wv, ws + WTH_OFF,
                                               ws + WTL_OFF);
  proj_kernel<<<dim3(2, 256), 512, 0, stream>>>(
      x, ws + WTH_OFF, ws + WTL_OFF, ws + QH_OFF, ws + QL_OFF, ws + KH_OFF,
      ws + KL_OFF, ws + VT_OFF);
  attn_kernel<<<256, 512, 0, stream>>>(ws + QH_OFF, ws + QL_OFF, ws + KH_OFF,
                                       ws + KL_OFF, ws + VT_OFF, out);
}

// Round 5
// 410.429 us; speedup vs baseline: 1.4308x; 1.4308x over previous
//
#include <hip/hip_runtime.h>
#include <math.h>

#define B_ 8
#define T_ 2048
#define D_ 2048
#define H_ 128
#define M_ (B_ * T_)

typedef __bf16 bf16x8 __attribute__((ext_vector_type(8)));
typedef __bf16 bf16x4 __attribute__((ext_vector_type(4)));
typedef float f32x4 __attribute__((ext_vector_type(4)));

#define MFMA(a, b, c) __builtin_amdgcn_mfma_f32_16x16x32_bf16(a, b, c, 0, 0, 0)

// ws layout (bf16 elements)
#define QH_OFF 0
#define QL_OFF (1 * 2097152)  // M_*H_
#define KH_OFF (2 * 2097152)
#define KL_OFF (3 * 2097152)
#define VT_OFF (4 * 2097152)        // vt[b][h][t]
#define WTH_OFF (5 * 2097152)       // wt_hi[z*128+n][k]
#define WTL_OFF (WTH_OFF + 786432)  // 3*128*2048

// ---------------- prep: W[k][n] fp32 -> Wt_hi/lo[n][k] bf16 ----------------
__global__ __launch_bounds__(256) void prep_kernel(
    const float* __restrict__ Wq, const float* __restrict__ Wk,
    const float* __restrict__ Wv, __bf16* __restrict__ wt_hi,
    __bf16* __restrict__ wt_lo) {
  const int z = blockIdx.y;
  const int k0 = blockIdx.x * 64;
  const float* W = z == 0 ? Wq : z == 1 ? Wk : Wv;
  __shared__ float tile[64][132];
  const int t = threadIdx.x;
#pragma unroll
  for (int it = 0; it < 8; ++it) {
    int f4 = it * 256 + t;  // 2048 float4 = 64 rows x 32
    int row = f4 >> 5, c = (f4 & 31) << 2;
    *(float4*)&tile[row][c] = *(const float4*)&W[(size_t)(k0 + row) * H_ + c];
  }
  __syncthreads();
  int n = t >> 1, kh = (t & 1) << 5;
  __bf16 h[32], l[32];
#pragma unroll
  for (int kk = 0; kk < 32; ++kk) {
    float x = tile[kh + kk][n];
    __bf16 hi = (__bf16)x;
    h[kk] = hi;
    l[kk] = (__bf16)(x - (float)hi);
  }
  size_t base = (size_t)(z * H_ + n) * D_ + k0 + kh;
#pragma unroll
  for (int c = 0; c < 4; ++c) {
    *(bf16x8*)&wt_hi[base + c * 8] = *(bf16x8*)&h[c * 8];
    *(bf16x8*)&wt_lo[base + c * 8] = *(bf16x8*)&l[c * 8];
  }
}

// ---------------- proj: block-shared-LDS split-bf16 MFMA -------------------
// 256 blocks x 512 thr (8 waves). Block = 64m x 384n (q|k|v fused).
// Per kstep: W-tile (384x32 hi/lo) + X-tile (64x32 -> hi/lo) staged to LDS
// ONCE, shared by all 8 waves. Wave wv = 64m x 48n (mg4 x nt3, 36 MFMA).
// Register prefetch of kstep+1's W/X keeps global loads off the barrier path.
#define WSTR 36  // W row stride in bf16 (72 B): b64 frag reads, conflict-free
#define XSTR 72  // X row-pair stride (32 hi | 32 lo | 8 pad) = 144 B

__global__ __launch_bounds__(512, 2) void proj_kernel(
    const float* __restrict__ X, const __bf16* __restrict__ wt_hi,
    const __bf16* __restrict__ wt_lo, __bf16* __restrict__ qh,
    __bf16* __restrict__ ql, __bf16* __restrict__ kh,
    __bf16* __restrict__ kl, __bf16* __restrict__ vt) {
  __shared__ __align__(16) __bf16 Wh[384 * WSTR];  // 27648 B
  __shared__ __align__(16) __bf16 Wl[384 * WSTR];  // 27648 B
  __shared__ __align__(16) __bf16 Xs[64 * XSTR];   // 9216 B  (total 64512)
  const int t = threadIdx.x;
  const int wv = t >> 6, lane = t & 63;
  const int l15 = lane & 15, quad = lane >> 4, q8 = quad * 8;
  const int m0 = blockIdx.x * 64;
  const int nb = wv * 48;
  // staging maps
  const int xm = t >> 3, xk = (t & 7) << 2;  // X: 64 rows x 8 col-quads
  const float* xgp = X + (size_t)(m0 + xm) * D_ + xk;
  f32x4 acc[4][3] = {};
  // prefetch registers for kstep 0
  float4 xr = *(const float4*)xgp;
  bf16x8 whr[3], wlr[3];
#pragma unroll
  for (int p = 0; p < 3; ++p) {
    int c = t + (p << 9);
    int n = c >> 2, o = (c & 3) << 3;
    whr[p] = *(const bf16x8*)(wt_hi + (size_t)n * D_ + o);
    wlr[p] = *(const bf16x8*)(wt_lo + (size_t)n * D_ + o);
  }
  for (int ks = 0; ks < 64; ++ks) {
    __syncthreads();  // prior kstep's LDS reads complete
    {                 // X regs -> hi/lo LDS
      __bf16 h0 = (__bf16)xr.x, h1 = (__bf16)xr.y, h2 = (__bf16)xr.z,
             h3 = (__bf16)xr.w;
      bf16x4 hv = {h0, h1, h2, h3};
      bf16x4 lv = {(__bf16)(xr.x - (float)h0), (__bf16)(xr.y - (float)h1),
                   (__bf16)(xr.z - (float)h2), (__bf16)(xr.w - (float)h3)};
      *(bf16x4*)&Xs[xm * XSTR + xk] = hv;
      *(bf16x4*)&Xs[xm * XSTR + 32 + xk] = lv;
    }
#pragma unroll
    for (int p = 0; p < 3; ++p) {  // W regs -> LDS (b64 stores, 8B aligned)
      int c = t + (p << 9);
      int n = c >> 2, o = (c & 3) << 3;
      bf16x4 a, b, cc, d;
#pragma unroll
      for (int j = 0; j < 4; ++j) {
        a[j] = whr[p][j];
        b[j] = whr[p][j + 4];
        cc[j] = wlr[p][j];
        d[j] = wlr[p][j + 4];
      }
      *(bf16x4*)&Wh[n * WSTR + o] = a;
      *(bf16x4*)&Wh[n * WSTR + o + 4] = b;
      *(bf16x4*)&Wl[n * WSTR + o] = cc;
      *(bf16x4*)&Wl[n * WSTR + o + 4] = d;
    }
    if (ks < 63) {  // prefetch kstep+1 into regs
      const int ko = (ks + 1) << 5;
      xr = *(const float4*)(xgp + ko);
#pragma unroll
      for (int p = 0; p < 3; ++p) {
        int c = t + (p << 9);
        int n = c >> 2, o = (c & 3) << 3;
        whr[p] = *(const bf16x8*)(wt_hi + (size_t)n * D_ + ko + o);
        wlr[p] = *(const bf16x8*)(wt_lo + (size_t)n * D_ + ko + o);
      }
    }
    __syncthreads();  // staged tile visible
    bf16x8 ah[4], al[4];
#pragma unroll
    for (int mg = 0; mg < 4; ++mg) {
      ah[mg] = *(bf16x8*)&Xs[(mg * 16 + l15) * XSTR + q8];
      al[mg] = *(bf16x8*)&Xs[(mg * 16 + l15) * XSTR + 32 + q8];
    }
#pragma unroll
    for (int nt = 0; nt < 3; ++nt) {
      const int n = nb + nt * 16 + l15;
      bf16x4 b0 = *(bf16x4*)&Wh[n * WSTR + q8];
      bf16x4 b1 = *(bf16x4*)&Wh[n * WSTR + q8 + 4];
      bf16x4 b2 = *(bf16x4*)&Wl[n * WSTR + q8];
      bf16x4 b3 = *(bf16x4*)&Wl[n * WSTR + q8 + 4];
      bf16x8 bh, bl;
#pragma unroll
      for (int j = 0; j < 4; ++j) {
        bh[j] = b0[j];
        bh[j + 4] = b1[j];
        bl[j] = b2[j];
        bl[j + 4] = b3[j];
      }
#pragma unroll
      for (int mg = 0; mg < 4; ++mg) {
        acc[mg][nt] = MFMA(ah[mg], bh, acc[mg][nt]);
        acc[mg][nt] = MFMA(al[mg], bh, acc[mg][nt]);
        acc[mg][nt] = MFMA(ah[mg], bl, acc[mg][nt]);
      }
    }
  }
  // epilogue (C/D: col = l15 -> n, row = quad*4+reg -> m)
#pragma unroll
  for (int nt = 0; nt < 3; ++nt) {
    int ncb = nb + nt * 16;  // 16-aligned, never crosses a z boundary
    int z = ncb >> 7;
    int h = (ncb & 127) + l15;
#pragma unroll
    for (int mg = 0; mg < 4; ++mg) {
      int r0 = m0 + mg * 16 + quad * 4;
      if (z == 2) {
        int b = m0 >> 11;
        int tt0 = (m0 & 2047) + mg * 16 + quad * 4;
        bf16x4 pv = {(__bf16)acc[mg][nt][0], (__bf16)acc[mg][nt][1],
                     (__bf16)acc[mg][nt][2], (__bf16)acc[mg][nt][3]};
        *(bf16x4*)&vt[(size_t)(b * H_ + h) * T_ + tt0] = pv;
      } else {
        __bf16* dh = z == 0 ? qh : kh;
        __bf16* dl = z == 0 ? ql : kl;
#pragma unroll
        for (int reg = 0; reg < 4; ++reg) {
          float v = acc[mg][nt][reg];
          __bf16 hi = (__bf16)v;
          dh[(size_t)(r0 + reg) * H_ + h] = hi;
          dl[(size_t)(r0 + reg) * H_ + h] = (__bf16)(v - (float)hi);
        }
      }
    }
  }
}

// ---------------- attention: flash, split-bf16 QK (3-pass), bf16 PV --------
// (round-3 version, verbatim — known-good 180 µs-class)
__global__ __launch_bounds__(512, 2) void attn_kernel(
    const __bf16* __restrict__ qh, const __bf16* __restrict__ qlo,
    const __bf16* __restrict__ kh, const __bf16* __restrict__ klo,
    const __bf16* __restrict__ vt, float* __restrict__ out) {
  const int t = threadIdx.x;
  const int wv = t >> 6, st = wv >> 2, cw = wv & 3;
  const int lane = t & 63, l15 = lane & 15, quad = lane >> 4;
  const int j = blockIdx.x, b = j >> 5, pi = j & 31;
  const int qlidx = (st == 0) ? pi : 63 - pi;
  const int t0 = qlidx * 32;
  const int nkt = (qlidx >> 1) + 1;
  __shared__ __align__(16) __bf16 Pbuf[8][32 * 72];
  __shared__ __align__(16) float Obuf[2][32 * 132];
  __shared__ float mlb[2][4][32], llb[2][4][32];
  const size_t qrow0 = (size_t)b * T_ + t0;
  bf16x8 qfh[2][4], qfl[2][4];
#pragma unroll
  for (int mg = 0; mg < 2; ++mg)
#pragma unroll
    for (int ds = 0; ds < 4; ++ds) {
      size_t off = (qrow0 + mg * 16 + l15) * H_ + ds * 32 + quad * 8;
      qfh[mg][ds] = *(const bf16x8*)(qh + off);
      qfl[mg][ds] = *(const bf16x8*)(qlo + off);
    }
  f32x4 O[2][8] = {};
  float ms[2][4], ls[2][4];
#pragma unroll
  for (int mg = 0; mg < 2; ++mg)
#pragma unroll
    for (int reg = 0; reg < 4; ++reg) {
      ms[mg][reg] = -INFINITY;
      ls[mg][reg] = 0.f;
    }
  const __bf16* vtb = vt + (size_t)b * H_ * T_;
  const float scale = 11.313708498984761f;  // sqrt(128); ref multiplies
  for (int kt_i = cw; kt_i < nkt; kt_i += 4) {
    const int kt = kt_i * 64;
    f32x4 S[2][4] = {};
#pragma unroll
    for (int ds = 0; ds < 4; ++ds)
#pragma unroll
      for (int ct = 0; ct < 4; ++ct) {
        size_t koff =
            ((size_t)b * T_ + kt + ct * 16 + l15) * H_ + ds * 32 + quad * 8;
        bf16x8 bh = *(const bf16x8*)(kh + koff);
        bf16x8 bl = *(const bf16x8*)(klo + koff);
#pragma unroll
        for (int mg = 0; mg < 2; ++mg) {
          S[mg][ct] = MFMA(qfh[mg][ds], bh, S[mg][ct]);
          S[mg][ct] = MFMA(qfl[mg][ds], bh, S[mg][ct]);
          S[mg][ct] = MFMA(qfh[mg][ds], bl, S[mg][ct]);
        }
      }
    const bool diag = (kt_i == nkt - 1);
#pragma unroll
    for (int mg = 0; mg < 2; ++mg)
#pragma unroll
      for (int ct = 0; ct < 4; ++ct)
#pragma unroll
        for (int reg = 0; reg < 4; ++reg) {
          float s = S[mg][ct][reg] * scale;
          if (diag && (kt + ct * 16 + l15 > t0 + mg * 16 + quad * 4 + reg))
            s = -1e30f;
          S[mg][ct][reg] = s;
        }
    float al_[2][4];
#pragma unroll
    for (int mg = 0; mg < 2; ++mg)
#pragma unroll
      for (int reg = 0; reg < 4; ++reg) {
        float r = fmaxf(fmaxf(S[mg][0][reg], S[mg][1][reg]),
                        fmaxf(S[mg][2][reg], S[mg][3][reg]));
        r = fmaxf(r, __shfl_xor(r, 1));
        r = fmaxf(r, __shfl_xor(r, 2));
        r = fmaxf(r, __shfl_xor(r, 4));
        r = fmaxf(r, __shfl_xor(r, 8));
        float mn = fmaxf(ms[mg][reg], r);
        float a = __expf(ms[mg][reg] - mn);
        ms[mg][reg] = mn;
        float ps = 0.f;
#pragma unroll
        for (int ct = 0; ct < 4; ++ct) {
          float p = __expf(S[mg][ct][reg] - mn);
          S[mg][ct][reg] = p;
          ps += p;
        }
        ps += __shfl_xor(ps, 1);
        ps += __shfl_xor(ps, 2);
        ps += __shfl_xor(ps, 4);
        ps += __shfl_xor(ps, 8);
        ls[mg][reg] = ls[mg][reg] * a + ps;
        al_[mg][reg] = a;
      }
#pragma unroll
    for (int mg = 0; mg < 2; ++mg)
#pragma unroll
      for (int ht = 0; ht < 8; ++ht)
#pragma unroll
        for (int reg = 0; reg < 4; ++reg) O[mg][ht][reg] *= al_[mg][reg];
#pragma unroll
    for (int mg = 0; mg < 2; ++mg)
#pragma unroll
      for (int ct = 0; ct < 4; ++ct)
#pragma unroll
        for (int reg = 0; reg < 4; ++reg)
          Pbuf[wv][(mg * 16 + quad * 4 + reg) * 72 + ct * 16 + l15] =
              (__bf16)S[mg][ct][reg];
#pragma unroll
    for (int ks = 0; ks < 2; ++ks) {
      bf16x8 pf0 = *(bf16x8*)&Pbuf[wv][(l15)*72 + ks * 32 + quad * 8];
      bf16x8 pf1 = *(bf16x8*)&Pbuf[wv][(16 + l15) * 72 + ks * 32 + quad * 8];
#pragma unroll
      for (int ht = 0; ht < 8; ++ht) {
        bf16x8 vf = *(const bf16x8*)&vtb[(size_t)(ht * 16 + l15) * T_ + kt +
                                         ks * 32 + quad * 8];
        O[0][ht] = MFMA(pf0, vf, O[0][ht]);
        O[1][ht] = MFMA(pf1, vf, O[1][ht]);
      }
    }
  }
  if (l15 == 0) {
#pragma unroll
    for (int mg = 0; mg < 2; ++mg)
#pragma unroll
      for (int reg = 0; reg < 4; ++reg) {
        mlb[st][cw][mg * 16 + quad * 4 + reg] = ms[mg][reg];
        llb[st][cw][mg * 16 + quad * 4 + reg] = ls[mg][reg];
      }
  }
  for (int i = t; i < 2 * 32 * 132; i += 512) ((float*)Obuf)[i] = 0.f;
  __syncthreads();
  float aw[2][4];
#pragma unroll
  for (int mg = 0; mg < 2; ++mg)
#pragma unroll
    for (int reg = 0; reg < 4; ++reg) {
      int row = mg * 16 + quad * 4 + reg;
      float M = fmaxf(fmaxf(mlb[st][0][row], mlb[st][1][row]),
                      fmaxf(mlb[st][2][row], mlb[st][3][row]));
      float L = 0.f;
#pragma unroll
      for (int w = 0; w < 4; ++w)
        L += llb[st][w][row] * __expf(mlb[st][w][row] - M);
      aw[mg][reg] = __expf(ms[mg][reg] - M) / L;
    }
#pragma unroll
  for (int mg = 0; mg < 2; ++mg)
#pragma unroll
    for (int ht = 0; ht < 8; ++ht)
#pragma unroll
      for (int reg = 0; reg < 4; ++reg)
        atomicAdd(&Obuf[st][(mg * 16 + quad * 4 + reg) * 132 + ht * 16 + l15],
                  O[mg][ht][reg] * aw[mg][reg]);
  __syncthreads();
  {
    const int stw = t >> 8, tt = t & 255;
    const int qlw = (stw == 0) ? pi : 63 - pi;
    const size_t obase = ((size_t)b * T_ + qlw * 32) * H_;
#pragma unroll
    for (int i = 0; i < 4; ++i) {
      int f4 = i * 256 + tt;
      int row = f4 >> 5, c = (f4 & 31) << 2;
      *(float4*)&out[obase + (size_t)row * H_ + c] =
          *(float4*)&Obuf[stw][row * 132 + c];
    }
  }
}

extern "C" void kernel_launch(void* const* d_in, const int* in_sizes, int n_in,
                              void* d_out, int out_size, void* d_ws, size_t ws_size,
                              hipStream_t stream) {
  const float* x = (const float*)d_in[0];
  const float* Wq = (const float*)d_in[1];
  const float* Wk = (const float*)d_in[2];
  const float* Wv = (const float*)d_in[3];
  __bf16* ws = (__bf16*)d_ws;
  float* out = (float*)d_out;
  prep_kernel<<<dim3(32, 3), 256, 0, stream>>>(Wq, Wk, Wv, ws + WTH_OFF,
                                               ws + WTL_OFF);
  proj_kernel<<<256, 512, 0, stream>>>(x, ws + WTH_OFF, ws + WTL_OFF,
                                       ws + QH_OFF, ws + QL_OFF, ws + KH_OFF,
                                       ws + KL_OFF, ws + VT_OFF);
  attn_kernel<<<256, 512, 0, stream>>>(ws + QH_OFF, ws + QL_OFF, ws + KH_OFF,
                                       ws + KL_OFF, ws + VT_OFF, out);
}